// Round 8
// baseline (726.375 us; speedup 1.0000x reference)
//
#include <hip/hip_runtime.h>

#define B_  2048
#define N_  64
#define H_  4
#define FI  256
#define FO  256
#define HF  1024   // H*F_OUT
#define NB  8      // batches per persistent block
#define GRID (B_ / NB)   // 256 blocks = 1 per CU

typedef _Float16 f16;
typedef _Float16 f16x8 __attribute__((ext_vector_type(8)));
typedef _Float16 f16x4 __attribute__((ext_vector_type(4)));
typedef float f32x4 __attribute__((ext_vector_type(4)));

#define MFMA16(a,b,c) __builtin_amdgcn_mfma_f32_16x16x32_f16(a, b, c, 0, 0, 0)

// ---------------------------------------------------------------------------
// W prep: W [256][1024] f32 -> f16 MFMA B-fragments in workspace.
// layout: frag[kt(8)][ctg(64)][lane(64)][j(8)]
// element: W[kt*32 + (lane>>4)*8 + j][ctg*16 + (lane&15)]
// ---------------------------------------------------------------------------
__global__ __launch_bounds__(256) void prep_w_kernel(const float* __restrict__ W,
                                                     f16* __restrict__ wfrag) {
    int tid  = blockIdx.x * 256 + threadIdx.x;   // 0..32767
    int lane = tid & 63;
    int ctg  = (tid >> 6) & 63;
    int kt   = tid >> 12;                        // 0..7
    int krow = kt * 32 + (lane >> 4) * 8;
    int col  = ctg * 16 + (lane & 15);
    f16x8 v;
#pragma unroll
    for (int j = 0; j < 8; ++j)
        v[j] = (f16)W[(size_t)(krow + j) * HF + col];
    *((f16x8*)wfrag + tid) = v;
}

// ---------------------------------------------------------------------------
// Persistent fused GAT: grid=256, 1024 threads = 16 waves = (head w, quarter).
// Each block processes NB=8 batches; LDS staging double-buffered; next batch's
// input/adj prefetched into registers during GEMM1 and converted mid-compute.
// Per batch: 3 barriers. h strip stays in registers as MFMA B-frags (r6/r7
// permutation: k' = 32n5 + 8[n3n2] + 4n4 + [n1n0]); softmax in-register.
// LDS (92160 B):
//   [0, 65536)      sA[2]    input f16 [64][256], XOR-swizzled, double-buffered
//   [65536, 81920)  sAdjP[2] adj f16 [64 i][64 k'] permuted, swizzled, dbuf
//   [81920, 86016)  sCi   per-wave coeff_i partials [16][64] f32
//   [86016, 90112)  sCj   per-wave coeff_j partials [16][64] f32
//   [90112, 91136)  sCiS  summed coeff_i [4][64] f32
//   [91136, 92160)  sCjS  summed coeff_j [4][64] f32
// ---------------------------------------------------------------------------
#define SMEM_BYTES 92160
#define SADJ_OFF   65536
#define SCI_OFF    81920
#define SCJ_OFF    86016
#define SCIS_OFF   90112
#define SCJS_OFF   91136

__global__ __launch_bounds__(1024, 1) void gat_kernel(
    const float* __restrict__ input, const float* __restrict__ adj,
    const f16* __restrict__ wfrag, const float* __restrict__ a_i,
    const float* __restrict__ a_j, const float* __restrict__ bias,
    float* __restrict__ out)
{
    __shared__ unsigned char smem[SMEM_BYTES] __attribute__((aligned(16)));
    float* sCi  = (float*)(smem + SCI_OFF);
    float* sCj  = (float*)(smem + SCJ_OFF);
    float* sCiS = (float*)(smem + SCIS_OFF);
    float* sCjS = (float*)(smem + SCJS_OFF);

    const int tid  = threadIdx.x;
    const int wv   = tid >> 6;      // wave 0..15
    const int w    = wv >> 2;       // head 0..3
    const int ch2  = wv & 3;        // col-quarter 0..3
    const int lane = tid & 63;
    const int g    = lane >> 4;
    const int c15  = lane & 15;

    // per-tid staging coords (batch-independent)
    const int srow = tid >> 5;              // 0..31 (chunk row; +32 for 2nd)
    const int sk0  = (tid & 31) << 3;       // k offset, multiple of 8
    const int ai   = tid >> 3;              // adj row (tid<512)
    const int ajb  = tid & 7;               // adj 8-col block

    const int b0 = blockIdx.x * NB;

    // ---- prefetch state ----
    float4 fA0, fA1, fA2, fA3;   // raw f32 input (2 chunks x 32B)
    float4 fJ0, fJ1;             // raw f32 adj (tid<512)
    f16x8 pA0, pA1;              // converted input
    f16x4 pJlo, pJhi;            // converted adj (permuted halves)

    auto issue_loads = [&](int bb) {
        const float* p0 = input + (size_t)bb * (N_ * FI) + srow * FI + sk0;
        const float* p1 = p0 + 32 * FI;
        fA0 = ((const float4*)p0)[0];
        fA1 = ((const float4*)p0)[1];
        fA2 = ((const float4*)p1)[0];
        fA3 = ((const float4*)p1)[1];
        if (tid < 512) {
            const float* ap = adj + (size_t)bb * (N_ * N_) + ai * N_ + ajb * 8;
            fJ0 = ((const float4*)ap)[0];
            fJ1 = ((const float4*)ap)[1];
        }
    };
    auto convert_prefetch = [&]() {
        pA0[0] = (f16)fA0.x; pA0[1] = (f16)fA0.y; pA0[2] = (f16)fA0.z; pA0[3] = (f16)fA0.w;
        pA0[4] = (f16)fA1.x; pA0[5] = (f16)fA1.y; pA0[6] = (f16)fA1.z; pA0[7] = (f16)fA1.w;
        pA1[0] = (f16)fA2.x; pA1[1] = (f16)fA2.y; pA1[2] = (f16)fA2.z; pA1[3] = (f16)fA2.w;
        pA1[4] = (f16)fA3.x; pA1[5] = (f16)fA3.y; pA1[6] = (f16)fA3.z; pA1[7] = (f16)fA3.w;
        if (tid < 512) {
            pJlo[0] = (f16)fJ0.x; pJlo[1] = (f16)fJ0.y; pJlo[2] = (f16)fJ0.z; pJlo[3] = (f16)fJ0.w;
            pJhi[0] = (f16)fJ1.x; pJhi[1] = (f16)fJ1.y; pJhi[2] = (f16)fJ1.z; pJhi[3] = (f16)fJ1.w;
        }
    };
    auto write_batch = [&](int buf) {
        unsigned bufA = (unsigned)buf * 32768u;
        unsigned a0 = bufA + ((unsigned)(srow * 512 + sk0 * 2) ^ ((unsigned)(srow & 7) << 4));
        *(f16x8*)(smem + a0) = pA0;
        int srow1 = srow + 32;
        unsigned a1 = bufA + ((unsigned)(srow1 * 512 + sk0 * 2) ^ ((unsigned)(srow1 & 7) << 4));
        *(f16x8*)(smem + a1) = pA1;
        if (tid < 512) {
            unsigned bufJ = SADJ_OFF + (unsigned)buf * 8192u;
            unsigned k0p = (unsigned)(32 * (ajb >> 2) + 16 * (ajb & 1) + 4 * ((ajb >> 1) & 1));
            unsigned sw  = (unsigned)(ai & 7) << 4;
            *(f16x4*)(smem + bufJ + (((unsigned)(ai * 128) + k0p * 2) ^ sw)) = pJlo;
            *(f16x4*)(smem + bufJ + (((unsigned)(ai * 128) + (k0p + 8) * 2) ^ sw)) = pJhi;
        }
    };

    issue_loads(b0);
    convert_prefetch();

#pragma unroll 1
    for (int ib = 0; ib < NB; ++ib) {
        const int b   = b0 + ib;
        const int buf = ib & 1;
        const unsigned bufA = (unsigned)buf * 32768u;
        const unsigned bufJ = SADJ_OFF + (unsigned)buf * 8192u;

        write_batch(buf);
        __syncthreads();   // B0: staged data visible; prev iter fully retired

        if (ib + 1 < NB) issue_loads(b0 + ib + 1);   // fly across GEMM1-cc0

        // ---- GEMM1: this wave's 64 cols of head w; h kept in registers ----
        float ciP[16], cjP[16];
#pragma unroll
        for (int q = 0; q < 16; ++q) { ciP[q] = 0.f; cjP[q] = 0.f; }
        f16x8 hB[2][4];   // [kt2][ct]: slot jj = h[16*(2kt2+(jj>>2))+4g+(jj&3)][col]

#pragma unroll
        for (int cc = 0; cc < 2; ++cc) {
            f32x4 acc[4][2];
#pragma unroll
            for (int rt = 0; rt < 4; ++rt)
#pragma unroll
                for (int ctl = 0; ctl < 2; ++ctl) {
                    f32x4 z = {0.f, 0.f, 0.f, 0.f};
                    acc[rt][ctl] = z;
                }
#pragma unroll
            for (int kt = 0; kt < 8; ++kt) {
                f16x8 aF[4];
#pragma unroll
                for (int rt = 0; rt < 4; ++rt) {
                    int row = rt * 16 + c15;
                    unsigned addr = bufA + (((unsigned)(row * 512 + (kt * 32 + g * 8) * 2))
                                            ^ ((unsigned)(row & 7) << 4));
                    aF[rt] = *(const f16x8*)(smem + addr);
                }
                f16x8 bF[2];
#pragma unroll
                for (int ctl = 0; ctl < 2; ++ctl) {
                    int ctg = w * 16 + ch2 * 4 + cc * 2 + ctl;
                    bF[ctl] = *((const f16x8*)wfrag + ((kt * 64 + ctg) * 64 + lane));
                }
#pragma unroll
                for (int rt = 0; rt < 4; ++rt)
#pragma unroll
                    for (int ctl = 0; ctl < 2; ++ctl)
                        acc[rt][ctl] = MFMA16(aF[rt], bF[ctl], acc[rt][ctl]);
            }
            // epilogue: coeff partials + pack h into B-frag registers
#pragma unroll
            for (int ctl = 0; ctl < 2; ++ctl) {
                int ct = cc * 2 + ctl;
                int colg = w * FO + ch2 * 64 + ct * 16 + c15;
                float aIc = a_i[colg];
                float aJc = a_j[colg];
#pragma unroll
                for (int rt = 0; rt < 4; ++rt) {
#pragma unroll
                    for (int r = 0; r < 4; ++r) {
                        float v = acc[rt][ctl][r];
                        ciP[rt * 4 + r] += v * aIc;
                        cjP[rt * 4 + r] += v * aJc;
                        hB[rt >> 1][ct][4 * (rt & 1) + r] = (f16)v;
                    }
                }
            }
            // after cc=0: convert prefetch (vmcnt wait lands here, behind MFMA;
            // frees the 24 raw-f32 regs before the cc=1 register peak)
            if (cc == 0 && ib + 1 < NB) convert_prefetch();
        }

        // ---- coeff reduce over the 16 c15-lanes of each g-group ----
#pragma unroll
        for (int s = 1; s < 16; s <<= 1) {
#pragma unroll
            for (int q = 0; q < 16; ++q) {
                ciP[q] += __shfl_xor(ciP[q], s);
                cjP[q] += __shfl_xor(cjP[q], s);
            }
        }
        if (c15 == 0) {
#pragma unroll
            for (int q = 0; q < 16; ++q) {
                int node = (q >> 2) * 16 + g * 4 + (q & 3);
                sCi[wv * 64 + node] = ciP[q];
                sCj[wv * 64 + node] = cjP[q];
            }
        }
        __syncthreads();   // B1

        // ---- cross-wave coeff sums (per head) ----
        if (tid < 512) {
            int wq    = tid >> 7;
            int which = (tid >> 6) & 1;
            int node  = tid & 63;
            const float* src = (which == 0 ? sCi : sCj) + (wq * 4) * 64 + node;
            float s = src[0] + src[64] + src[128] + src[192];
            (which == 0 ? sCiS : sCjS)[wq * 64 + node] = s;
        }
        __syncthreads();   // B2

        // ---- per row-tile: in-register softmax (permuted layout) + GEMM2 ----
#pragma unroll 1
        for (int it = 0; it < 4; ++it) {
            int i = it * 16 + c15;
            float ci = sCiS[w * 64 + i];
            unsigned sw = (unsigned)(i & 7) << 4;
            f16x8 adjv0 = *(const f16x8*)(smem + bufJ + (((unsigned)(i * 128) + (g * 8) * 2) ^ sw));
            f16x8 adjv1 = *(const f16x8*)(smem + bufJ + (((unsigned)(i * 128) + (32 + g * 8) * 2) ^ sw));
            float cj[16];
#pragma unroll
            for (int t = 0; t < 4; ++t) {
                float4 c4 = *(const float4*)(sCjS + w * 64 + t * 16 + 4 * g);
                cj[t * 4 + 0] = c4.x; cj[t * 4 + 1] = c4.y;
                cj[t * 4 + 2] = c4.z; cj[t * 4 + 3] = c4.w;
            }
            float sv[16], av[16];
#pragma unroll
            for (int q = 0; q < 16; ++q)
                av[q] = (float)(q < 8 ? adjv0[q & 7] : adjv1[q & 7]);
            float m = -1e30f;
#pragma unroll
            for (int q = 0; q < 16; ++q) {
                float e = ci + cj[q];
                e = fmaxf(e, 0.2f * e);          // leaky_relu slope 0.2
                float s = e * av[q];
                sv[q] = s;
                m = fmaxf(m, s);
            }
            m = fmaxf(m, __shfl_xor(m, 16));
            m = fmaxf(m, __shfl_xor(m, 32));
            float sum = 0.f;
#pragma unroll
            for (int q = 0; q < 16; ++q) { float p = __expf(sv[q] - m); sv[q] = p; sum += p; }
            sum += __shfl_xor(sum, 16);
            sum += __shfl_xor(sum, 32);
            float rs = 1.0f / sum;
            f16x8 atF[2];
#pragma unroll
            for (int jj = 0; jj < 8; ++jj) {
                atF[0][jj] = (f16)(sv[jj] * rs * av[jj]);
                atF[1][jj] = (f16)(sv[8 + jj] * rs * av[8 + jj]);
            }
            f32x4 acc2[4];
#pragma unroll
            for (int ct = 0; ct < 4; ++ct) {
                f32x4 z = {0.f, 0.f, 0.f, 0.f};
                acc2[ct] = z;
            }
#pragma unroll
            for (int kt2 = 0; kt2 < 2; ++kt2)
#pragma unroll
                for (int ct = 0; ct < 4; ++ct)
                    acc2[ct] = MFMA16(atF[kt2], hB[kt2][ct], acc2[ct]);
#pragma unroll
            for (int ct = 0; ct < 4; ++ct) {
                int colg = w * FO + ch2 * 64 + ct * 16 + c15;
                float bv = bias[colg];
#pragma unroll
                for (int r = 0; r < 4; ++r) {
                    int row = it * 16 + g * 4 + r;
                    out[((size_t)b * N_ + row) * HF + colg] = acc2[ct][r] + bv;
                }
            }
        }
    }
}

extern "C" void kernel_launch(void* const* d_in, const int* in_sizes, int n_in,
                              void* d_out, int out_size, void* d_ws, size_t ws_size,
                              hipStream_t stream) {
    const float* input = (const float*)d_in[0];
    const float* adj   = (const float*)d_in[1];
    const float* W     = (const float*)d_in[2];
    const float* a_i   = (const float*)d_in[3];
    const float* a_j   = (const float*)d_in[4];
    const float* bias  = (const float*)d_in[5];
    float* outp  = (float*)d_out;
    f16*   wfrag = (f16*)d_ws;   // 512 KB

    prep_w_kernel<<<128, 256, 0, stream>>>(W, wfrag);
    gat_kernel<<<GRID, 1024, 0, stream>>>(input, adj, wfrag, a_i, a_j, bias, outp);
}

// Round 9
// 718.149 us; speedup vs baseline: 1.0115x; 1.0115x over previous
//
#include <hip/hip_runtime.h>

#define B_  2048
#define N_  64
#define H_  4
#define FI  256
#define FO  256
#define HF  1024   // H*F_OUT
#define NB  8      // batches per persistent block
#define GRID (B_ / NB)   // 256 blocks = 1 per CU

typedef _Float16 f16;
typedef _Float16 f16x8 __attribute__((ext_vector_type(8)));
typedef _Float16 f16x4 __attribute__((ext_vector_type(4)));
typedef float f32x4 __attribute__((ext_vector_type(4)));

#define MFMA16(a,b,c) __builtin_amdgcn_mfma_f32_16x16x32_f16(a, b, c, 0, 0, 0)

// ---------------------------------------------------------------------------
// W prep: W [256][1024] f32 -> f16 MFMA B-fragments in workspace.
// layout: frag[kt(8)][ctg(64)][lane(64)][j(8)]
// element: W[kt*32 + (lane>>4)*8 + j][ctg*16 + (lane&15)]
// ---------------------------------------------------------------------------
__global__ __launch_bounds__(256) void prep_w_kernel(const float* __restrict__ W,
                                                     f16* __restrict__ wfrag) {
    int tid  = blockIdx.x * 256 + threadIdx.x;   // 0..32767
    int lane = tid & 63;
    int ctg  = (tid >> 6) & 63;
    int kt   = tid >> 12;                        // 0..7
    int krow = kt * 32 + (lane >> 4) * 8;
    int col  = ctg * 16 + (lane & 15);
    f16x8 v;
#pragma unroll
    for (int j = 0; j < 8; ++j)
        v[j] = (f16)W[(size_t)(krow + j) * HF + col];
    *((f16x8*)wfrag + tid) = v;
}

// ---------------------------------------------------------------------------
// Persistent fused GAT: grid=256, 1024 threads = 16 waves = (head w, quarter).
// NB=8 batches per block, LDS double-buffered. NO long-lived register
// prefetch (r8's spill): next-batch global loads issue after B1 (coeff regs
// just died), B2's implicit vmcnt(0) drain absorbs their latency, convert +
// ds_write immediately after B2 -> staging regs dead before softmax.
// GEMM2 stores drain asynchronously across the loop, overlapping next GEMM1.
// LDS (92160 B):
//   [0, 65536)      sA[2]    input f16 [64][256], XOR-swizzled, dbuf
//   [65536, 81920)  sAdjP[2] adj f16 [64 i][64 k'] permuted, swizzled, dbuf
//   [81920, 86016)  sCi   per-wave coeff_i partials [16][64] f32
//   [86016, 90112)  sCj   per-wave coeff_j partials [16][64] f32
//   [90112, 91136)  sCiS  summed coeff_i [4][64] f32
//   [91136, 92160)  sCjS  summed coeff_j [4][64] f32
// ---------------------------------------------------------------------------
#define SMEM_BYTES 92160
#define SADJ_OFF   65536
#define SCI_OFF    81920
#define SCJ_OFF    86016
#define SCIS_OFF   90112
#define SCJS_OFF   91136

__global__ __launch_bounds__(1024, 1) void gat_kernel(
    const float* __restrict__ input, const float* __restrict__ adj,
    const f16* __restrict__ wfrag, const float* __restrict__ a_i,
    const float* __restrict__ a_j, const float* __restrict__ bias,
    float* __restrict__ out)
{
    __shared__ unsigned char smem[SMEM_BYTES] __attribute__((aligned(16)));
    float* sCi  = (float*)(smem + SCI_OFF);
    float* sCj  = (float*)(smem + SCJ_OFF);
    float* sCiS = (float*)(smem + SCIS_OFF);
    float* sCjS = (float*)(smem + SCJS_OFF);

    const int tid  = threadIdx.x;
    const int wv   = tid >> 6;      // wave 0..15
    const int w    = wv >> 2;       // head 0..3
    const int ch2  = wv & 3;        // col-quarter 0..3
    const int lane = tid & 63;
    const int g    = lane >> 4;
    const int c15  = lane & 15;

    // per-tid staging coords (batch-independent)
    const int srow = tid >> 5;              // 0..31 (chunk row; +32 for 2nd)
    const int sk0  = (tid & 31) << 3;       // k offset, multiple of 8
    const int ai   = tid >> 3;              // adj row (tid<512)
    const int ajb  = tid & 7;               // adj 8-col block

    const int b0 = blockIdx.x * NB;

    // staging write helper: convert 6 float4 -> f16 and write swizzled
    auto stage_write = [&](int buf, const float4& A0, const float4& A1,
                           const float4& A2, const float4& A3,
                           const float4& J0, const float4& J1) {
        unsigned bufA = (unsigned)buf * 32768u;
        f16x8 h8;
        h8[0] = (f16)A0.x; h8[1] = (f16)A0.y; h8[2] = (f16)A0.z; h8[3] = (f16)A0.w;
        h8[4] = (f16)A1.x; h8[5] = (f16)A1.y; h8[6] = (f16)A1.z; h8[7] = (f16)A1.w;
        unsigned a0 = bufA + ((unsigned)(srow * 512 + sk0 * 2) ^ ((unsigned)(srow & 7) << 4));
        *(f16x8*)(smem + a0) = h8;
        f16x8 h9;
        h9[0] = (f16)A2.x; h9[1] = (f16)A2.y; h9[2] = (f16)A2.z; h9[3] = (f16)A2.w;
        h9[4] = (f16)A3.x; h9[5] = (f16)A3.y; h9[6] = (f16)A3.z; h9[7] = (f16)A3.w;
        int srow1 = srow + 32;
        unsigned a1 = bufA + ((unsigned)(srow1 * 512 + sk0 * 2) ^ ((unsigned)(srow1 & 7) << 4));
        *(f16x8*)(smem + a1) = h9;
        if (tid < 512) {
            unsigned bufJ = SADJ_OFF + (unsigned)buf * 8192u;
            f16x4 lo, hi;
            lo[0] = (f16)J0.x; lo[1] = (f16)J0.y; lo[2] = (f16)J0.z; lo[3] = (f16)J0.w;
            hi[0] = (f16)J1.x; hi[1] = (f16)J1.y; hi[2] = (f16)J1.z; hi[3] = (f16)J1.w;
            unsigned k0p = (unsigned)(32 * (ajb >> 2) + 16 * (ajb & 1) + 4 * ((ajb >> 1) & 1));
            unsigned sw  = (unsigned)(ai & 7) << 4;
            *(f16x4*)(smem + bufJ + (((unsigned)(ai * 128) + k0p * 2) ^ sw)) = lo;
            *(f16x4*)(smem + bufJ + (((unsigned)(ai * 128) + (k0p + 8) * 2) ^ sw)) = hi;
        }
    };

    // ---- prologue: stage batch b0 into buf 0 ----
    {
        const float* p0 = input + (size_t)b0 * (N_ * FI) + srow * FI + sk0;
        const float* p1 = p0 + 32 * FI;
        float4 A0 = ((const float4*)p0)[0];
        float4 A1 = ((const float4*)p0)[1];
        float4 A2 = ((const float4*)p1)[0];
        float4 A3 = ((const float4*)p1)[1];
        float4 J0 = {0,0,0,0}, J1 = {0,0,0,0};
        if (tid < 512) {
            const float* ap = adj + (size_t)b0 * (N_ * N_) + ai * N_ + ajb * 8;
            J0 = ((const float4*)ap)[0];
            J1 = ((const float4*)ap)[1];
        }
        stage_write(0, A0, A1, A2, A3, J0, J1);
    }

#pragma unroll 1
    for (int ib = 0; ib < NB; ++ib) {
        const int b   = b0 + ib;
        const int buf = ib & 1;
        const unsigned bufA = (unsigned)buf * 32768u;
        const unsigned bufJ = SADJ_OFF + (unsigned)buf * 8192u;

        __syncthreads();   // B0: staged data for ib visible; prev GEMM2 LDS reads done

        // ---- GEMM1: this wave's 64 cols of head w; h kept in registers ----
        float ciP[16], cjP[16];
#pragma unroll
        for (int q = 0; q < 16; ++q) { ciP[q] = 0.f; cjP[q] = 0.f; }
        f16x8 hB[2][4];   // [kt2][ct]: slot jj = h[16*(2kt2+(jj>>2))+4g+(jj&3)][col]

#pragma unroll
        for (int cc = 0; cc < 2; ++cc) {
            f32x4 acc[4][2];
#pragma unroll
            for (int rt = 0; rt < 4; ++rt)
#pragma unroll
                for (int ctl = 0; ctl < 2; ++ctl) {
                    f32x4 z = {0.f, 0.f, 0.f, 0.f};
                    acc[rt][ctl] = z;
                }
#pragma unroll
            for (int kt = 0; kt < 8; ++kt) {
                f16x8 aF[4];
#pragma unroll
                for (int rt = 0; rt < 4; ++rt) {
                    int row = rt * 16 + c15;
                    unsigned addr = bufA + (((unsigned)(row * 512 + (kt * 32 + g * 8) * 2))
                                            ^ ((unsigned)(row & 7) << 4));
                    aF[rt] = *(const f16x8*)(smem + addr);
                }
                f16x8 bF[2];
#pragma unroll
                for (int ctl = 0; ctl < 2; ++ctl) {
                    int ctg = w * 16 + ch2 * 4 + cc * 2 + ctl;
                    bF[ctl] = *((const f16x8*)wfrag + ((kt * 64 + ctg) * 64 + lane));
                }
#pragma unroll
                for (int rt = 0; rt < 4; ++rt)
#pragma unroll
                    for (int ctl = 0; ctl < 2; ++ctl)
                        acc[rt][ctl] = MFMA16(aF[rt], bF[ctl], acc[rt][ctl]);
            }
            // epilogue: coeff partials + pack h into B-frag registers
#pragma unroll
            for (int ctl = 0; ctl < 2; ++ctl) {
                int ct = cc * 2 + ctl;
                int colg = w * FO + ch2 * 64 + ct * 16 + c15;
                float aIc = a_i[colg];
                float aJc = a_j[colg];
#pragma unroll
                for (int rt = 0; rt < 4; ++rt) {
#pragma unroll
                    for (int r = 0; r < 4; ++r) {
                        float v = acc[rt][ctl][r];
                        ciP[rt * 4 + r] += v * aIc;
                        cjP[rt * 4 + r] += v * aJc;
                        hB[rt >> 1][ct][4 * (rt & 1) + r] = (f16)v;
                    }
                }
            }
        }

        // ---- coeff reduce over the 16 c15-lanes of each g-group ----
#pragma unroll
        for (int s = 1; s < 16; s <<= 1) {
#pragma unroll
            for (int q = 0; q < 16; ++q) {
                ciP[q] += __shfl_xor(ciP[q], s);
                cjP[q] += __shfl_xor(cjP[q], s);
            }
        }
        if (c15 == 0) {
#pragma unroll
            for (int q = 0; q < 16; ++q) {
                int node = (q >> 2) * 16 + g * 4 + (q & 3);
                sCi[wv * 64 + node] = ciP[q];
                sCj[wv * 64 + node] = cjP[q];
            }
        }
        __syncthreads();   // B1

        // ---- issue next-batch loads (short-lived; drained at B2) ----
        float4 A0, A1, A2, A3, J0, J1;
        const bool pf = (ib + 1 < NB);
        if (pf) {
            const float* p0 = input + (size_t)(b + 1) * (N_ * FI) + srow * FI + sk0;
            const float* p1 = p0 + 32 * FI;
            A0 = ((const float4*)p0)[0];
            A1 = ((const float4*)p0)[1];
            A2 = ((const float4*)p1)[0];
            A3 = ((const float4*)p1)[1];
            if (tid < 512) {
                const float* ap = adj + (size_t)(b + 1) * (N_ * N_) + ai * N_ + ajb * 8;
                J0 = ((const float4*)ap)[0];
                J1 = ((const float4*)ap)[1];
            }
        }

        // ---- cross-wave coeff sums (per head) ----
        if (tid < 512) {
            int wq    = tid >> 7;
            int which = (tid >> 6) & 1;
            int node  = tid & 63;
            const float* src = (which == 0 ? sCi : sCj) + (wq * 4) * 64 + node;
            float s = src[0] + src[64] + src[128] + src[192];
            (which == 0 ? sCiS : sCjS)[wq * 64 + node] = s;
        }
        __syncthreads();   // B2 (implicit vmcnt(0) completes the loads above)

        // ---- write next-batch staging to the other buffer (regs die here) ----
        if (pf) stage_write(buf ^ 1, A0, A1, A2, A3, J0, J1);

        // ---- per row-tile: in-register softmax (permuted layout) + GEMM2 ----
#pragma unroll 1
        for (int it = 0; it < 4; ++it) {
            int i = it * 16 + c15;
            float ci = sCiS[w * 64 + i];
            unsigned sw = (unsigned)(i & 7) << 4;
            f16x8 adjv0 = *(const f16x8*)(smem + bufJ + (((unsigned)(i * 128) + (g * 8) * 2) ^ sw));
            f16x8 adjv1 = *(const f16x8*)(smem + bufJ + (((unsigned)(i * 128) + (32 + g * 8) * 2) ^ sw));
            float cj[16];
#pragma unroll
            for (int t = 0; t < 4; ++t) {
                float4 c4 = *(const float4*)(sCjS + w * 64 + t * 16 + 4 * g);
                cj[t * 4 + 0] = c4.x; cj[t * 4 + 1] = c4.y;
                cj[t * 4 + 2] = c4.z; cj[t * 4 + 3] = c4.w;
            }
            float sv[16], av[16];
#pragma unroll
            for (int q = 0; q < 16; ++q)
                av[q] = (float)(q < 8 ? adjv0[q & 7] : adjv1[q & 7]);
            float m = -1e30f;
#pragma unroll
            for (int q = 0; q < 16; ++q) {
                float e = ci + cj[q];
                e = fmaxf(e, 0.2f * e);          // leaky_relu slope 0.2
                float s = e * av[q];
                sv[q] = s;
                m = fmaxf(m, s);
            }
            m = fmaxf(m, __shfl_xor(m, 16));
            m = fmaxf(m, __shfl_xor(m, 32));
            float sum = 0.f;
#pragma unroll
            for (int q = 0; q < 16; ++q) { float p = __expf(sv[q] - m); sv[q] = p; sum += p; }
            sum += __shfl_xor(sum, 16);
            sum += __shfl_xor(sum, 32);
            float rs = 1.0f / sum;
            f16x8 atF[2];
#pragma unroll
            for (int jj = 0; jj < 8; ++jj) {
                atF[0][jj] = (f16)(sv[jj] * rs * av[jj]);
                atF[1][jj] = (f16)(sv[8 + jj] * rs * av[8 + jj]);
            }
            f32x4 acc2[4];
#pragma unroll
            for (int ct = 0; ct < 4; ++ct) {
                f32x4 z = {0.f, 0.f, 0.f, 0.f};
                acc2[ct] = z;
            }
#pragma unroll
            for (int kt2 = 0; kt2 < 2; ++kt2)
#pragma unroll
                for (int ct = 0; ct < 4; ++ct)
                    acc2[ct] = MFMA16(atF[kt2], hB[kt2][ct], acc2[ct]);
#pragma unroll
            for (int ct = 0; ct < 4; ++ct) {
                int colg = w * FO + ch2 * 64 + ct * 16 + c15;
                float bv = bias[colg];
#pragma unroll
                for (int r = 0; r < 4; ++r) {
                    int row = it * 16 + g * 4 + r;
                    out[((size_t)b * N_ + row) * HF + colg] = acc2[ct][r] + bv;
                }
            }
        }
    }
}

extern "C" void kernel_launch(void* const* d_in, const int* in_sizes, int n_in,
                              void* d_out, int out_size, void* d_ws, size_t ws_size,
                              hipStream_t stream) {
    const float* input = (const float*)d_in[0];
    const float* adj   = (const float*)d_in[1];
    const float* W     = (const float*)d_in[2];
    const float* a_i   = (const float*)d_in[3];
    const float* a_j   = (const float*)d_in[4];
    const float* bias  = (const float*)d_in[5];
    float* outp  = (float*)d_out;
    f16*   wfrag = (f16*)d_ws;   // 512 KB

    prep_w_kernel<<<128, 256, 0, stream>>>(W, wfrag);
    gat_kernel<<<GRID, 1024, 0, stream>>>(input, adj, wfrag, a_i, a_j, bias, outp);
}

// Round 10
// 713.803 us; speedup vs baseline: 1.0176x; 1.0061x over previous
//
#include <hip/hip_runtime.h>

#define B_  2048
#define N_  64
#define H_  4
#define FI  256
#define FO  256
#define HF  1024   // H*F_OUT
#define NB  8      // batches per persistent block
#define GRID (B_ / NB)   // 256 blocks = 1 per CU

typedef _Float16 f16;
typedef _Float16 f16x8 __attribute__((ext_vector_type(8)));
typedef _Float16 f16x4 __attribute__((ext_vector_type(4)));
typedef float f32x4 __attribute__((ext_vector_type(4)));

#define MFMA16(a,b,c) __builtin_amdgcn_mfma_f32_16x16x32_f16(a, b, c, 0, 0, 0)

// ---------------------------------------------------------------------------
// W prep: W [256][1024] f32 -> f16 MFMA B-fragments in workspace.
// layout: frag[kt(8)][ctg(64)][lane(64)][j(8)]
// element: W[kt*32 + (lane>>4)*8 + j][ctg*16 + (lane&15)]
// ---------------------------------------------------------------------------
__global__ __launch_bounds__(256) void prep_w_kernel(const float* __restrict__ W,
                                                     f16* __restrict__ wfrag) {
    int tid  = blockIdx.x * 256 + threadIdx.x;   // 0..32767
    int lane = tid & 63;
    int ctg  = (tid >> 6) & 63;
    int kt   = tid >> 12;                        // 0..7
    int krow = kt * 32 + (lane >> 4) * 8;
    int col  = ctg * 16 + (lane & 15);
    f16x8 v;
#pragma unroll
    for (int j = 0; j < 8; ++j)
        v[j] = (f16)W[(size_t)(krow + j) * HF + col];
    *((f16x8*)wfrag + tid) = v;
}

// ---------------------------------------------------------------------------
// Persistent fused GAT: grid=256, 1024 threads = 16 waves = (head w, quarter).
// NB=8 batches per block, LDS double-buffered; next-batch loads issue at B1,
// drain at B2, ds_write after B2 (regs die before softmax).
// r8/r9 showed VGPR_Count=64 + ~850MB scratch spill under __launch_bounds__
// (1024,1): the backend's memory-bound wave-limiter heuristic silently
// targeted 8 waves/EU. amdgpu_waves_per_eu(4,4) pins the budget to 128 VGPRs
// (16 waves/CU = what we actually run) and overrides the heuristic.
// LDS (92160 B):
//   [0, 65536)      sA[2]    input f16 [64][256], XOR-swizzled, dbuf
//   [65536, 81920)  sAdjP[2] adj f16 [64 i][64 k'] permuted, swizzled, dbuf
//   [81920, 86016)  sCi   per-wave coeff_i partials [16][64] f32
//   [86016, 90112)  sCj   per-wave coeff_j partials [16][64] f32
//   [90112, 91136)  sCiS  summed coeff_i [4][64] f32
//   [91136, 92160)  sCjS  summed coeff_j [4][64] f32
// ---------------------------------------------------------------------------
#define SMEM_BYTES 92160
#define SADJ_OFF   65536
#define SCI_OFF    81920
#define SCJ_OFF    86016
#define SCIS_OFF   90112
#define SCJS_OFF   91136

__global__ __launch_bounds__(1024)
__attribute__((amdgpu_waves_per_eu(4, 4)))
void gat_kernel(
    const float* __restrict__ input, const float* __restrict__ adj,
    const f16* __restrict__ wfrag, const float* __restrict__ a_i,
    const float* __restrict__ a_j, const float* __restrict__ bias,
    float* __restrict__ out)
{
    __shared__ unsigned char smem[SMEM_BYTES] __attribute__((aligned(16)));
    float* sCi  = (float*)(smem + SCI_OFF);
    float* sCj  = (float*)(smem + SCJ_OFF);
    float* sCiS = (float*)(smem + SCIS_OFF);
    float* sCjS = (float*)(smem + SCJS_OFF);

    const int tid  = threadIdx.x;
    const int wv   = tid >> 6;      // wave 0..15
    const int w    = wv >> 2;       // head 0..3
    const int ch2  = wv & 3;        // col-quarter 0..3
    const int lane = tid & 63;
    const int g    = lane >> 4;
    const int c15  = lane & 15;

    // per-tid staging coords (batch-independent)
    const int srow = tid >> 5;              // 0..31 (chunk row; +32 for 2nd)
    const int sk0  = (tid & 31) << 3;       // k offset, multiple of 8
    const int ai   = tid >> 3;              // adj row (tid<512)
    const int ajb  = tid & 7;               // adj 8-col block

    const int b0 = blockIdx.x * NB;

    // staging write helper: convert 6 float4 -> f16 and write swizzled
    auto stage_write = [&](int buf, const float4& A0, const float4& A1,
                           const float4& A2, const float4& A3,
                           const float4& J0, const float4& J1) {
        unsigned bufA = (unsigned)buf * 32768u;
        f16x8 h8;
        h8[0] = (f16)A0.x; h8[1] = (f16)A0.y; h8[2] = (f16)A0.z; h8[3] = (f16)A0.w;
        h8[4] = (f16)A1.x; h8[5] = (f16)A1.y; h8[6] = (f16)A1.z; h8[7] = (f16)A1.w;
        unsigned a0 = bufA + ((unsigned)(srow * 512 + sk0 * 2) ^ ((unsigned)(srow & 7) << 4));
        *(f16x8*)(smem + a0) = h8;
        f16x8 h9;
        h9[0] = (f16)A2.x; h9[1] = (f16)A2.y; h9[2] = (f16)A2.z; h9[3] = (f16)A2.w;
        h9[4] = (f16)A3.x; h9[5] = (f16)A3.y; h9[6] = (f16)A3.z; h9[7] = (f16)A3.w;
        int srow1 = srow + 32;
        unsigned a1 = bufA + ((unsigned)(srow1 * 512 + sk0 * 2) ^ ((unsigned)(srow1 & 7) << 4));
        *(f16x8*)(smem + a1) = h9;
        if (tid < 512) {
            unsigned bufJ = SADJ_OFF + (unsigned)buf * 8192u;
            f16x4 lo, hi;
            lo[0] = (f16)J0.x; lo[1] = (f16)J0.y; lo[2] = (f16)J0.z; lo[3] = (f16)J0.w;
            hi[0] = (f16)J1.x; hi[1] = (f16)J1.y; hi[2] = (f16)J1.z; hi[3] = (f16)J1.w;
            unsigned k0p = (unsigned)(32 * (ajb >> 2) + 16 * (ajb & 1) + 4 * ((ajb >> 1) & 1));
            unsigned sw  = (unsigned)(ai & 7) << 4;
            *(f16x4*)(smem + bufJ + (((unsigned)(ai * 128) + k0p * 2) ^ sw)) = lo;
            *(f16x4*)(smem + bufJ + (((unsigned)(ai * 128) + (k0p + 8) * 2) ^ sw)) = hi;
        }
    };

    // ---- prologue: stage batch b0 into buf 0 ----
    {
        const float* p0 = input + (size_t)b0 * (N_ * FI) + srow * FI + sk0;
        const float* p1 = p0 + 32 * FI;
        float4 A0 = ((const float4*)p0)[0];
        float4 A1 = ((const float4*)p0)[1];
        float4 A2 = ((const float4*)p1)[0];
        float4 A3 = ((const float4*)p1)[1];
        float4 J0 = {0,0,0,0}, J1 = {0,0,0,0};
        if (tid < 512) {
            const float* ap = adj + (size_t)b0 * (N_ * N_) + ai * N_ + ajb * 8;
            J0 = ((const float4*)ap)[0];
            J1 = ((const float4*)ap)[1];
        }
        stage_write(0, A0, A1, A2, A3, J0, J1);
    }

#pragma unroll 1
    for (int ib = 0; ib < NB; ++ib) {
        const int b   = b0 + ib;
        const int buf = ib & 1;
        const unsigned bufA = (unsigned)buf * 32768u;
        const unsigned bufJ = SADJ_OFF + (unsigned)buf * 8192u;

        __syncthreads();   // B0: staged data for ib visible; prev GEMM2 LDS reads done

        // ---- GEMM1: this wave's 64 cols of head w; h kept in registers ----
        float ciP[16], cjP[16];
#pragma unroll
        for (int q = 0; q < 16; ++q) { ciP[q] = 0.f; cjP[q] = 0.f; }
        f16x8 hB[2][4];   // [kt2][ct]: slot jj = h[16*(2kt2+(jj>>2))+4g+(jj&3)][col]

#pragma unroll
        for (int cc = 0; cc < 2; ++cc) {
            f32x4 acc[4][2];
#pragma unroll
            for (int rt = 0; rt < 4; ++rt)
#pragma unroll
                for (int ctl = 0; ctl < 2; ++ctl) {
                    f32x4 z = {0.f, 0.f, 0.f, 0.f};
                    acc[rt][ctl] = z;
                }
#pragma unroll
            for (int kt = 0; kt < 8; ++kt) {
                f16x8 aF[4];
#pragma unroll
                for (int rt = 0; rt < 4; ++rt) {
                    int row = rt * 16 + c15;
                    unsigned addr = bufA + (((unsigned)(row * 512 + (kt * 32 + g * 8) * 2))
                                            ^ ((unsigned)(row & 7) << 4));
                    aF[rt] = *(const f16x8*)(smem + addr);
                }
                f16x8 bF[2];
#pragma unroll
                for (int ctl = 0; ctl < 2; ++ctl) {
                    int ctg = w * 16 + ch2 * 4 + cc * 2 + ctl;
                    bF[ctl] = *((const f16x8*)wfrag + ((kt * 64 + ctg) * 64 + lane));
                }
#pragma unroll
                for (int rt = 0; rt < 4; ++rt)
#pragma unroll
                    for (int ctl = 0; ctl < 2; ++ctl)
                        acc[rt][ctl] = MFMA16(aF[rt], bF[ctl], acc[rt][ctl]);
            }
            // epilogue: coeff partials + pack h into B-frag registers
#pragma unroll
            for (int ctl = 0; ctl < 2; ++ctl) {
                int ct = cc * 2 + ctl;
                int colg = w * FO + ch2 * 64 + ct * 16 + c15;
                float aIc = a_i[colg];
                float aJc = a_j[colg];
#pragma unroll
                for (int rt = 0; rt < 4; ++rt) {
#pragma unroll
                    for (int r = 0; r < 4; ++r) {
                        float v = acc[rt][ctl][r];
                        ciP[rt * 4 + r] += v * aIc;
                        cjP[rt * 4 + r] += v * aJc;
                        hB[rt >> 1][ct][4 * (rt & 1) + r] = (f16)v;
                    }
                }
            }
        }

        // ---- coeff reduce over the 16 c15-lanes of each g-group ----
#pragma unroll
        for (int s = 1; s < 16; s <<= 1) {
#pragma unroll
            for (int q = 0; q < 16; ++q) {
                ciP[q] += __shfl_xor(ciP[q], s);
                cjP[q] += __shfl_xor(cjP[q], s);
            }
        }
        if (c15 == 0) {
#pragma unroll
            for (int q = 0; q < 16; ++q) {
                int node = (q >> 2) * 16 + g * 4 + (q & 3);
                sCi[wv * 64 + node] = ciP[q];
                sCj[wv * 64 + node] = cjP[q];
            }
        }
        __syncthreads();   // B1

        // ---- issue next-batch loads (short-lived; drained at B2) ----
        float4 A0, A1, A2, A3, J0, J1;
        const bool pf = (ib + 1 < NB);
        if (pf) {
            const float* p0 = input + (size_t)(b + 1) * (N_ * FI) + srow * FI + sk0;
            const float* p1 = p0 + 32 * FI;
            A0 = ((const float4*)p0)[0];
            A1 = ((const float4*)p0)[1];
            A2 = ((const float4*)p1)[0];
            A3 = ((const float4*)p1)[1];
            if (tid < 512) {
                const float* ap = adj + (size_t)(b + 1) * (N_ * N_) + ai * N_ + ajb * 8;
                J0 = ((const float4*)ap)[0];
                J1 = ((const float4*)ap)[1];
            }
        }

        // ---- cross-wave coeff sums (per head) ----
        if (tid < 512) {
            int wq    = tid >> 7;
            int which = (tid >> 6) & 1;
            int node  = tid & 63;
            const float* src = (which == 0 ? sCi : sCj) + (wq * 4) * 64 + node;
            float s = src[0] + src[64] + src[128] + src[192];
            (which == 0 ? sCiS : sCjS)[wq * 64 + node] = s;
        }
        __syncthreads();   // B2 (implicit vmcnt(0) completes the loads above)

        // ---- write next-batch staging to the other buffer (regs die here) ----
        if (pf) stage_write(buf ^ 1, A0, A1, A2, A3, J0, J1);

        // ---- per row-tile: in-register softmax (permuted layout) + GEMM2 ----
#pragma unroll 1
        for (int it = 0; it < 4; ++it) {
            int i = it * 16 + c15;
            float ci = sCiS[w * 64 + i];
            unsigned sw = (unsigned)(i & 7) << 4;
            f16x8 adjv0 = *(const f16x8*)(smem + bufJ + (((unsigned)(i * 128) + (g * 8) * 2) ^ sw));
            f16x8 adjv1 = *(const f16x8*)(smem + bufJ + (((unsigned)(i * 128) + (32 + g * 8) * 2) ^ sw));
            float cj[16];
#pragma unroll
            for (int t = 0; t < 4; ++t) {
                float4 c4 = *(const float4*)(sCjS + w * 64 + t * 16 + 4 * g);
                cj[t * 4 + 0] = c4.x; cj[t * 4 + 1] = c4.y;
                cj[t * 4 + 2] = c4.z; cj[t * 4 + 3] = c4.w;
            }
            float sv[16], av[16];
#pragma unroll
            for (int q = 0; q < 16; ++q)
                av[q] = (float)(q < 8 ? adjv0[q & 7] : adjv1[q & 7]);
            float m = -1e30f;
#pragma unroll
            for (int q = 0; q < 16; ++q) {
                float e = ci + cj[q];
                e = fmaxf(e, 0.2f * e);          // leaky_relu slope 0.2
                float s = e * av[q];
                sv[q] = s;
                m = fmaxf(m, s);
            }
            m = fmaxf(m, __shfl_xor(m, 16));
            m = fmaxf(m, __shfl_xor(m, 32));
            float sum = 0.f;
#pragma unroll
            for (int q = 0; q < 16; ++q) { float p = __expf(sv[q] - m); sv[q] = p; sum += p; }
            sum += __shfl_xor(sum, 16);
            sum += __shfl_xor(sum, 32);
            float rs = 1.0f / sum;
            f16x8 atF[2];
#pragma unroll
            for (int jj = 0; jj < 8; ++jj) {
                atF[0][jj] = (f16)(sv[jj] * rs * av[jj]);
                atF[1][jj] = (f16)(sv[8 + jj] * rs * av[8 + jj]);
            }
            f32x4 acc2[4];
#pragma unroll
            for (int ct = 0; ct < 4; ++ct) {
                f32x4 z = {0.f, 0.f, 0.f, 0.f};
                acc2[ct] = z;
            }
#pragma unroll
            for (int kt2 = 0; kt2 < 2; ++kt2)
#pragma unroll
                for (int ct = 0; ct < 4; ++ct)
                    acc2[ct] = MFMA16(atF[kt2], hB[kt2][ct], acc2[ct]);
#pragma unroll
            for (int ct = 0; ct < 4; ++ct) {
                int colg = w * FO + ch2 * 64 + ct * 16 + c15;
                float bv = bias[colg];
#pragma unroll
                for (int r = 0; r < 4; ++r) {
                    int row = it * 16 + g * 4 + r;
                    out[((size_t)b * N_ + row) * HF + colg] = acc2[ct][r] + bv;
                }
            }
        }
    }
}

extern "C" void kernel_launch(void* const* d_in, const int* in_sizes, int n_in,
                              void* d_out, int out_size, void* d_ws, size_t ws_size,
                              hipStream_t stream) {
    const float* input = (const float*)d_in[0];
    const float* adj   = (const float*)d_in[1];
    const float* W     = (const float*)d_in[2];
    const float* a_i   = (const float*)d_in[3];
    const float* a_j   = (const float*)d_in[4];
    const float* bias  = (const float*)d_in[5];
    float* outp  = (float*)d_out;
    f16*   wfrag = (f16*)d_ws;   // 512 KB

    prep_w_kernel<<<128, 256, 0, stream>>>(W, wfrag);
    gat_kernel<<<GRID, 1024, 0, stream>>>(input, adj, wfrag, a_i, a_j, bias, outp);
}